// Round 6
// baseline (38300.113 us; speedup 1.0000x reference)
//
#include <hip/hip_runtime.h>
#include <math.h>

// GRU layer: B=64, T=512, I=512, H=1024, fp32.
//
// Evidence so far:
//  r1: cg::grid.sync() persistent = 100us/step, 17.9MB/step HBM writes
//      (SYSTEM-scope flush to HBM every sync). Concept ok, scope wrong.
//  r5: removing 1/3 of per-step work left step time unchanged (~28us)
//      -> per-LAUNCH fixed cost (~20us) dominates the 512-launch loop.
//
// This round: persistent kernel + hand-rolled AGENT-scope barrier.
//  - xproj (parallel, proven): xpre[g][t][j][b] = x.W_i_g  (one launch).
//  - gru_persist: 256 blocks (1/CU, coop-launch guarantees residency),
//    256 threads; 512 steps inside one kernel. Per step: 8 K-chunks of
//    h@W_h_* staged in LDS from hpack[parity][j][b] (contiguous 256KB,
//    coalesced; linear LDS [k][b] is bank-conflict-free: lane=b).
//    Barrier: __threadfence() (wbl2 -> L3) + agent-scope atomicAdd on a
//    monotonic counter; tid0 spins on relaxed agent loads (L3 reads, no
//    inv per poll, s_sleep backoff); __threadfence() (inv) + syncthreads.
//  - Accumulation order bit-identical to r5 (absmax must stay 0.00390625).
//  - Fallbacks: coop-launch failure -> r5's 512-launch gru_step_h;
//    tiny ws -> r0 gru_step_full.

#define BB 64
#define TT 512
#define II 512
#define HH 1024
#define JB 4
#define CK 128
#define PAD 132
#define XJ 16

__device__ __forceinline__ void fma4(float4& a, const float4 xv, const float4 w) {
    a.x += xv.x * w.x;
    a.y += xv.y * w.y;
    a.z += xv.z * w.z;
    a.w += xv.w * w.w;
}

// ---------------------------------------------------------------------------
// Phase 1: x-projections for all t (unchanged from r5).
// ---------------------------------------------------------------------------
__global__ __launch_bounds__(256) void xproj(
    const float* __restrict__ x,
    const float* __restrict__ Wir, const float* __restrict__ Wiz,
    const float* __restrict__ Win, float* __restrict__ xpre)
{
    __shared__ float xs[BB][PAD];
    const int tid  = threadIdx.x;
    const int b    = tid & 63;
    const int w    = tid >> 6;
    const int bid  = (int)blockIdx.x;
    const int t    = bid >> 6;
    const int jgrp = bid & 63;
    const int j0   = __builtin_amdgcn_readfirstlane(jgrp * XJ + w * 4);

    float4 acc[4][3];
#pragma unroll
    for (int jj = 0; jj < 4; ++jj)
#pragma unroll
        for (int g = 0; g < 3; ++g)
            acc[jj][g] = {0.f, 0.f, 0.f, 0.f};

    const float* xbase = x + (size_t)t * II;
    for (int kc = 0; kc < II / CK; ++kc) {
#pragma unroll
        for (int i = 0; i < 8; ++i) {
            int f   = tid + 256 * i;
            int row = f >> 5;
            int c4  = f & 31;
            *(float4*)&xs[row][c4 * 4] =
                *(const float4*)(xbase + (size_t)row * (TT * II) + kc * CK + c4 * 4);
        }
        __syncthreads();
        const float* xsrow = &xs[b][0];
#pragma unroll
        for (int k4 = 0; k4 < CK / 4; ++k4) {
            float4 xv = *(const float4*)(xsrow + k4 * 4);
#pragma unroll
            for (int jj = 0; jj < 4; ++jj) {
                const size_t wof = (size_t)(j0 + jj) * II + kc * CK + k4 * 4;
                fma4(acc[jj][0], xv, *(const float4*)(Wir + wof));
                fma4(acc[jj][1], xv, *(const float4*)(Wiz + wof));
                fma4(acc[jj][2], xv, *(const float4*)(Win + wof));
            }
        }
        __syncthreads();
    }

#pragma unroll
    for (int jj = 0; jj < 4; ++jj) {
        const int j = j0 + jj;
#pragma unroll
        for (int g = 0; g < 3; ++g) {
            float s = acc[jj][g].x + acc[jj][g].y + acc[jj][g].z + acc[jj][g].w;
            xpre[(((size_t)g * TT + t) * HH + j) * BB + b] = s;
        }
    }
}

// ---------------------------------------------------------------------------
// Phase 2: persistent recurrent kernel. grid=256 (1/CU), 256 threads.
// ---------------------------------------------------------------------------
__global__ __launch_bounds__(256) void gru_persist(
    const float* __restrict__ Whr, const float* __restrict__ Whz,
    const float* __restrict__ Whn,
    const float* __restrict__ bir, const float* __restrict__ bhr,
    const float* __restrict__ biz, const float* __restrict__ bhz,
    const float* __restrict__ bin_, const float* __restrict__ bhn,
    const float* __restrict__ xpre,
    float* __restrict__ out, float* __restrict__ hpack,
    unsigned* __restrict__ bar)
{
    __shared__ float hs[CK * BB];      // 32KB linear [k][b]; lane=b -> conflict-free
    const int tid = threadIdx.x;
    const int b   = tid & 63;
    const int jg  = tid >> 6;
    const int j   = __builtin_amdgcn_readfirstlane((int)blockIdx.x * JB + jg);

    const float bir_j = bir[j], bhr_j = bhr[j];
    const float biz_j = biz[j], bhz_j = bhz[j];
    const float bin_j = bin_[j], bhn_j = bhn[j];

    const size_t HB = (size_t)HH * BB;

    for (int t = 0; t < TT; ++t) {
        const float* hp_prev = hpack + (size_t)((t + 1) & 1) * HB;  // (t-1)&1
        float*       hp_cur  = hpack + (size_t)(t & 1) * HB;

        const float xr  = xpre[(((size_t)0 * TT + t) * HH + j) * BB + b];
        const float xz  = xpre[(((size_t)1 * TT + t) * HH + j) * BB + b];
        const float xn0 = xpre[(((size_t)2 * TT + t) * HH + j) * BB + b];

        float4 aR  = {0.f, 0.f, 0.f, 0.f};
        float4 aZ  = {0.f, 0.f, 0.f, 0.f};
        float4 aHN = {0.f, 0.f, 0.f, 0.f};
        float hprev = 0.f;

        if (t > 0) {
            hprev = hp_prev[(size_t)j * BB + b];
#pragma unroll 1
            for (int kc = 0; kc < HH / CK; ++kc) {
                const float* src = hp_prev + (size_t)kc * (CK * BB);
#pragma unroll
                for (int i = 0; i < 8; ++i) {
                    const int f = tid + 256 * i;      // float4 index in 32KB chunk
                    *(float4*)&hs[f * 4] = *(const float4*)(src + (size_t)f * 4);
                }
                __syncthreads();
                const float* wr = Whr + (size_t)j * HH + kc * CK;
                const float* wz = Whz + (size_t)j * HH + kc * CK;
                const float* wn = Whn + (size_t)j * HH + kc * CK;
#pragma unroll
                for (int k4 = 0; k4 < CK / 4; ++k4) {
                    const float4 wrv = *(const float4*)(wr + k4 * 4);
                    const float4 wzv = *(const float4*)(wz + k4 * 4);
                    const float4 wnv = *(const float4*)(wn + k4 * 4);
                    const float h0 = hs[(k4 * 4 + 0) * 64 + b];
                    const float h1 = hs[(k4 * 4 + 1) * 64 + b];
                    const float h2 = hs[(k4 * 4 + 2) * 64 + b];
                    const float h3 = hs[(k4 * 4 + 3) * 64 + b];
                    aR.x  += h0 * wrv.x; aR.y  += h1 * wrv.y;
                    aR.z  += h2 * wrv.z; aR.w  += h3 * wrv.w;
                    aZ.x  += h0 * wzv.x; aZ.y  += h1 * wzv.y;
                    aZ.z  += h2 * wzv.z; aZ.w  += h3 * wzv.w;
                    aHN.x += h0 * wnv.x; aHN.y += h1 * wnv.y;
                    aHN.z += h2 * wnv.z; aHN.w += h3 * wnv.w;
                }
                __syncthreads();
            }
        }

        // epilogue (same order as r5 -> absmax unchanged)
        float rpre = (aR.x + aR.y + aR.z + aR.w) + xr + bir_j + bhr_j;
        float zpre = (aZ.x + aZ.y + aZ.z + aZ.w) + xz + biz_j + bhz_j;
        float hn   = (aHN.x + aHN.y + aHN.z + aHN.w) + bhn_j;
        float xn   = xn0 + bin_j;

        float r = 1.f / (1.f + __expf(-rpre));
        float z = 1.f / (1.f + __expf(-zpre));
        float n = tanhf(xn + r * hn);
        float hnew = (1.f - z) * n + z * hprev;

        out[(size_t)b * (TT * HH) + (size_t)t * HH + j] = hnew;
        hp_cur[(size_t)j * BB + b] = hnew;

        // ---- agent-scope grid barrier (monotonic counter) ----
        __syncthreads();                       // all stores issued+drained
        if (tid == 0) {
            __threadfence();                   // release: L2 dirty -> L3
            __hip_atomic_fetch_add(bar, 1u, __ATOMIC_RELAXED,
                                   __HIP_MEMORY_SCOPE_AGENT);
            const unsigned tgt = 256u * (unsigned)(t + 1);
            while (__hip_atomic_load(bar, __ATOMIC_RELAXED,
                                     __HIP_MEMORY_SCOPE_AGENT) < tgt)
                __builtin_amdgcn_s_sleep(2);
            __threadfence();                   // acquire: inv L1/L2
        }
        __syncthreads();
    }
}

// ---------------------------------------------------------------------------
// Fallback A: r5's per-step h kernel (if coop launch is rejected).
// ---------------------------------------------------------------------------
__global__ __launch_bounds__(256) void gru_step_h(
    const float* __restrict__ Whr, const float* __restrict__ Whz,
    const float* __restrict__ Whn,
    const float* __restrict__ bir, const float* __restrict__ bhr,
    const float* __restrict__ biz, const float* __restrict__ bhz,
    const float* __restrict__ bin_, const float* __restrict__ bhn,
    const float* __restrict__ xpre,
    float* __restrict__ out, int t)
{
    __shared__ float xs[BB][PAD];
    const int tid = threadIdx.x;
    const int b   = tid & 63;
    const int jg  = tid >> 6;
    const int j   = __builtin_amdgcn_readfirstlane((int)blockIdx.x * JB + jg);

    const float bir_j = bir[j], bhr_j = bhr[j];
    const float biz_j = biz[j], bhz_j = bhz[j];
    const float bin_j = bin_[j], bhn_j = bhn[j];
    const float xr  = xpre[(((size_t)0 * TT + t) * HH + j) * BB + b];
    const float xz  = xpre[(((size_t)1 * TT + t) * HH + j) * BB + b];
    const float xn0 = xpre[(((size_t)2 * TT + t) * HH + j) * BB + b];
    float hprev = 0.f;
    if (t > 0)
        hprev = out[(size_t)b * (TT * HH) + (size_t)(t - 1) * HH + j];

    float4 aR  = {0.f, 0.f, 0.f, 0.f};
    float4 aZ  = {0.f, 0.f, 0.f, 0.f};
    float4 aHN = {0.f, 0.f, 0.f, 0.f};

    if (t > 0) {
        const float* hbase = out + (size_t)(t - 1) * HH;
        for (int kc = 0; kc < HH / CK; ++kc) {
#pragma unroll
            for (int i = 0; i < 8; ++i) {
                int f   = tid + 256 * i;
                int row = f >> 5;
                int c4  = f & 31;
                *(float4*)&xs[row][c4 * 4] =
                    *(const float4*)(hbase + (size_t)row * (TT * HH) + kc * CK + c4 * 4);
            }
            __syncthreads();
            const float* xsrow = &xs[b][0];
            const float* wr = Whr + (size_t)j * HH + kc * CK;
            const float* wz = Whz + (size_t)j * HH + kc * CK;
            const float* wn = Whn + (size_t)j * HH + kc * CK;
#pragma unroll
            for (int k4 = 0; k4 < CK / 4; ++k4) {
                float4 xv = *(const float4*)(xsrow + k4 * 4);
                fma4(aR,  xv, *(const float4*)(wr + k4 * 4));
                fma4(aZ,  xv, *(const float4*)(wz + k4 * 4));
                fma4(aHN, xv, *(const float4*)(wn + k4 * 4));
            }
            __syncthreads();
        }
    }

    float rpre = (aR.x + aR.y + aR.z + aR.w) + xr + bir_j + bhr_j;
    float zpre = (aZ.x + aZ.y + aZ.z + aZ.w) + xz + biz_j + bhz_j;
    float hn   = (aHN.x + aHN.y + aHN.z + aHN.w) + bhn_j;
    float xn   = xn0 + bin_j;

    float r = 1.f / (1.f + __expf(-rpre));
    float z = 1.f / (1.f + __expf(-zpre));
    float n = tanhf(xn + r * hn);

    out[(size_t)b * (TT * HH) + (size_t)t * HH + j] = (1.f - z) * n + z * hprev;
}

// ---------------------------------------------------------------------------
// Fallback B: r0 monolithic step (tiny ws).
// ---------------------------------------------------------------------------
__device__ __forceinline__ void accum_chunk(
    const float* __restrict__ xsrow,
    const float* __restrict__ wr, const float* __restrict__ wz,
    const float* __restrict__ wn,
    float4& aR, float4& aZ, float4& aN)
{
#pragma unroll
    for (int k4 = 0; k4 < CK / 4; ++k4) {
        float4 xv = *(const float4*)(xsrow + k4 * 4);
        fma4(aR, xv, *(const float4*)(wr + k4 * 4));
        fma4(aZ, xv, *(const float4*)(wz + k4 * 4));
        fma4(aN, xv, *(const float4*)(wn + k4 * 4));
    }
}

__global__ __launch_bounds__(256) void gru_step_full(
    const float* __restrict__ x,
    const float* __restrict__ Wir, const float* __restrict__ Whr,
    const float* __restrict__ Wiz, const float* __restrict__ Whz,
    const float* __restrict__ Win, const float* __restrict__ Whn,
    const float* __restrict__ bir, const float* __restrict__ bhr,
    const float* __restrict__ biz, const float* __restrict__ bhz,
    const float* __restrict__ bin_, const float* __restrict__ bhn,
    float* __restrict__ out, int t)
{
    __shared__ float xs[BB][PAD];
    const int tid = threadIdx.x;
    const int b   = tid & 63;
    const int jg  = tid >> 6;
    const int j   = __builtin_amdgcn_readfirstlane((int)blockIdx.x * JB + jg);

    float4 aR  = {0.f, 0.f, 0.f, 0.f};
    float4 aZ  = {0.f, 0.f, 0.f, 0.f};
    float4 aXN = {0.f, 0.f, 0.f, 0.f};
    float4 aHN = {0.f, 0.f, 0.f, 0.f};

    const float* xbase = x + (size_t)t * II;
    for (int kc = 0; kc < II / CK; ++kc) {
#pragma unroll
        for (int i = 0; i < 8; ++i) {
            int f   = tid + 256 * i;
            int row = f >> 5;
            int c4  = f & 31;
            *(float4*)&xs[row][c4 * 4] =
                *(const float4*)(xbase + (size_t)row * (TT * II) + kc * CK + c4 * 4);
        }
        __syncthreads();
        accum_chunk(&xs[b][0],
                    Wir + (size_t)j * II + kc * CK,
                    Wiz + (size_t)j * II + kc * CK,
                    Win + (size_t)j * II + kc * CK,
                    aR, aZ, aXN);
        __syncthreads();
    }

    if (t > 0) {
        const float* hbase = out + (size_t)(t - 1) * HH;
        for (int kc = 0; kc < HH / CK; ++kc) {
#pragma unroll
            for (int i = 0; i < 8; ++i) {
                int f   = tid + 256 * i;
                int row = f >> 5;
                int c4  = f & 31;
                *(float4*)&xs[row][c4 * 4] =
                    *(const float4*)(hbase + (size_t)row * (TT * HH) + kc * CK + c4 * 4);
            }
            __syncthreads();
            accum_chunk(&xs[b][0],
                        Whr + (size_t)j * HH + kc * CK,
                        Whz + (size_t)j * HH + kc * CK,
                        Whn + (size_t)j * HH + kc * CK,
                        aR, aZ, aHN);
            __syncthreads();
        }
    }

    float rpre = (aR.x + aR.y + aR.z + aR.w) + bir[j] + bhr[j];
    float zpre = (aZ.x + aZ.y + aZ.z + aZ.w) + biz[j] + bhz[j];
    float hn   = (aHN.x + aHN.y + aHN.z + aHN.w) + bhn[j];
    float xn   = (aXN.x + aXN.y + aXN.z + aXN.w) + bin_[j];

    float r = 1.f / (1.f + __expf(-rpre));
    float z = 1.f / (1.f + __expf(-zpre));
    float n = tanhf(xn + r * hn);

    float hprev = (t > 0) ? out[(size_t)b * (TT * HH) + (size_t)(t - 1) * HH + j] : 0.f;
    out[(size_t)b * (TT * HH) + (size_t)t * HH + j] = (1.f - z) * n + z * hprev;
}

extern "C" void kernel_launch(void* const* d_in, const int* in_sizes, int n_in,
                              void* d_out, int out_size, void* d_ws, size_t ws_size,
                              hipStream_t stream) {
    (void)in_sizes; (void)n_in; (void)out_size;

    const float* x    = (const float*)d_in[0];
    const float* Wir  = (const float*)d_in[1];
    const float* bir  = (const float*)d_in[2];
    const float* Whr  = (const float*)d_in[3];
    const float* bhr  = (const float*)d_in[4];
    const float* Wiz  = (const float*)d_in[5];
    const float* biz  = (const float*)d_in[6];
    const float* Whz  = (const float*)d_in[7];
    const float* bhz  = (const float*)d_in[8];
    const float* Win  = (const float*)d_in[9];
    const float* bin_ = (const float*)d_in[10];
    const float* Whn  = (const float*)d_in[11];
    const float* bhn  = (const float*)d_in[12];
    float* out = (float*)d_out;

    const size_t XPRE_BYTES  = (size_t)3 * TT * HH * BB * sizeof(float);  // 402.65 MB
    const size_t HPACK_BYTES = (size_t)2 * HH * BB * sizeof(float);       // 512 KB
    const size_t need = XPRE_BYTES + HPACK_BYTES + 256;

    if (d_ws != nullptr && ws_size >= need) {
        float*    xpre  = (float*)d_ws;
        float*    hpack = (float*)((char*)d_ws + XPRE_BYTES);
        unsigned* bar   = (unsigned*)((char*)d_ws + XPRE_BYTES + HPACK_BYTES);

        hipMemsetAsync(bar, 0, 64, stream);
        xproj<<<dim3(TT * 64), dim3(256), 0, stream>>>(x, Wir, Wiz, Win, xpre);

        void* args[] = { (void*)&Whr, (void*)&Whz, (void*)&Whn,
                         (void*)&bir, (void*)&bhr, (void*)&biz, (void*)&bhz,
                         (void*)&bin_, (void*)&bhn, (void*)&xpre,
                         (void*)&out, (void*)&hpack, (void*)&bar };
        hipError_t e = hipLaunchCooperativeKernel((const void*)gru_persist,
                                                  dim3(256), dim3(256),
                                                  args, 0, stream);
        if (e != hipSuccess) {
            // co-residency rejected: r5 fallback (proven correct, ~15.9ms)
            for (int t = 0; t < TT; ++t) {
                gru_step_h<<<dim3(HH / JB), dim3(256), 0, stream>>>(
                    Whr, Whz, Whn, bir, bhr, biz, bhz, bin_, bhn, xpre, out, t);
            }
        }
    } else {
        for (int t = 0; t < TT; ++t) {
            gru_step_full<<<dim3(HH / JB), dim3(256), 0, stream>>>(
                x, Wir, Whr, Wiz, Whz, Win, Whn,
                bir, bhr, biz, bhz, bin_, bhn, out, t);
        }
    }
}

// Round 7
// 20929.411 us; speedup vs baseline: 1.8300x; 1.8300x over previous
//
#include <hip/hip_runtime.h>
#include <math.h>

// GRU layer: B=64, T=512, I=512, H=1024, fp32.
//
// Evidence ledger:
//  r1: cg::grid.sync persistent -> 100us/step, system-scope flush. Dead.
//  r5: 512 launches, h-only steps: step time INDEPENDENT of work
//      -> ~20us fixed per-launch cost dominates.
//  r6: persistent + single-counter atomicAdd barrier: 65us/step barrier.
//      Correctness of agent-scope primitives PROVEN (passed, absmax same).
//      Cost theory: 256 serialized same-line far-RMWs + 256 waves
//      atomic-polling the same line. WRITE counters show small dirty set
//      (wbl2 walk is not the dominant cost).
//
// r7: persistent kernel, distributed-flag barrier (no RMW anywhere):
//   - flags[bid] monotonic step counter, 128B apart (one line per block).
//   - arrival: tid0: __threadfence (release, wbl2) + relaxed agent store.
//   - wait: thread tid spins ONLY on flags[tid] (256 pollers per line max,
//     spread over 256 lines), s_sleep backoff; then tid0 __threadfence
//     (acquire, inv) + __syncthreads.
//   - inner body = r5's gru_step_h VERBATIM (h staged from `out` rows into
//     xs[b][PAD] with float4 LDS reads; weights stream via scalar cache;
//     accumulation order identical -> absmax unchanged).
// Fallbacks: coop-launch rejected -> r5 512-launch path; tiny ws -> r0.

#define BB 64
#define TT 512
#define II 512
#define HH 1024
#define JB 4
#define CK 128
#define PAD 132
#define XJ 16
#define FLAG_STRIDE 32   // uints; 128B between block flags

__device__ __forceinline__ void fma4(float4& a, const float4 xv, const float4 w) {
    a.x += xv.x * w.x;
    a.y += xv.y * w.y;
    a.z += xv.z * w.z;
    a.w += xv.w * w.w;
}

// ---------------------------------------------------------------------------
// Phase 1: x-projections for all t (unchanged, proven).
// ---------------------------------------------------------------------------
__global__ __launch_bounds__(256) void xproj(
    const float* __restrict__ x,
    const float* __restrict__ Wir, const float* __restrict__ Wiz,
    const float* __restrict__ Win, float* __restrict__ xpre)
{
    __shared__ float xs[BB][PAD];
    const int tid  = threadIdx.x;
    const int b    = tid & 63;
    const int w    = tid >> 6;
    const int bid  = (int)blockIdx.x;
    const int t    = bid >> 6;
    const int jgrp = bid & 63;
    const int j0   = __builtin_amdgcn_readfirstlane(jgrp * XJ + w * 4);

    float4 acc[4][3];
#pragma unroll
    for (int jj = 0; jj < 4; ++jj)
#pragma unroll
        for (int g = 0; g < 3; ++g)
            acc[jj][g] = {0.f, 0.f, 0.f, 0.f};

    const float* xbase = x + (size_t)t * II;
    for (int kc = 0; kc < II / CK; ++kc) {
#pragma unroll
        for (int i = 0; i < 8; ++i) {
            int f   = tid + 256 * i;
            int row = f >> 5;
            int c4  = f & 31;
            *(float4*)&xs[row][c4 * 4] =
                *(const float4*)(xbase + (size_t)row * (TT * II) + kc * CK + c4 * 4);
        }
        __syncthreads();
        const float* xsrow = &xs[b][0];
#pragma unroll
        for (int k4 = 0; k4 < CK / 4; ++k4) {
            float4 xv = *(const float4*)(xsrow + k4 * 4);
#pragma unroll
            for (int jj = 0; jj < 4; ++jj) {
                const size_t wof = (size_t)(j0 + jj) * II + kc * CK + k4 * 4;
                fma4(acc[jj][0], xv, *(const float4*)(Wir + wof));
                fma4(acc[jj][1], xv, *(const float4*)(Wiz + wof));
                fma4(acc[jj][2], xv, *(const float4*)(Win + wof));
            }
        }
        __syncthreads();
    }

#pragma unroll
    for (int jj = 0; jj < 4; ++jj) {
        const int j = j0 + jj;
#pragma unroll
        for (int g = 0; g < 3; ++g) {
            float s = acc[jj][g].x + acc[jj][g].y + acc[jj][g].z + acc[jj][g].w;
            xpre[(((size_t)g * TT + t) * HH + j) * BB + b] = s;
        }
    }
}

// ---------------------------------------------------------------------------
// Phase 2: persistent recurrent kernel, distributed-flag barrier.
// grid = 256 (1/CU, coop residency), 256 threads.
// ---------------------------------------------------------------------------
__global__ __launch_bounds__(256) void gru_persist(
    const float* __restrict__ Whr, const float* __restrict__ Whz,
    const float* __restrict__ Whn,
    const float* __restrict__ bir, const float* __restrict__ bhr,
    const float* __restrict__ biz, const float* __restrict__ bhz,
    const float* __restrict__ bin_, const float* __restrict__ bhn,
    const float* __restrict__ xpre,
    float* __restrict__ out, unsigned* __restrict__ flags)
{
    __shared__ float xs[BB][PAD];
    const int tid = threadIdx.x;
    const int b   = tid & 63;
    const int jg  = tid >> 6;
    const int bid = (int)blockIdx.x;
    const int j   = __builtin_amdgcn_readfirstlane(bid * JB + jg);

    const float bir_j = bir[j], bhr_j = bhr[j];
    const float biz_j = biz[j], bhz_j = bhz[j];
    const float bin_j = bin_[j], bhn_j = bhn[j];

    unsigned* myflag = flags + (size_t)bid * FLAG_STRIDE;
    unsigned* watch  = flags + (size_t)tid * FLAG_STRIDE;

    for (int t = 0; t < TT; ++t) {
        const float xr  = xpre[(((size_t)0 * TT + t) * HH + j) * BB + b];
        const float xz  = xpre[(((size_t)1 * TT + t) * HH + j) * BB + b];
        const float xn0 = xpre[(((size_t)2 * TT + t) * HH + j) * BB + b];

        float4 aR  = {0.f, 0.f, 0.f, 0.f};
        float4 aZ  = {0.f, 0.f, 0.f, 0.f};
        float4 aHN = {0.f, 0.f, 0.f, 0.f};
        float hprev = 0.f;

        if (t > 0) {
            hprev = out[(size_t)b * (TT * HH) + (size_t)(t - 1) * HH + j];
            const float* hbase = out + (size_t)(t - 1) * HH;
#pragma unroll 1
            for (int kc = 0; kc < HH / CK; ++kc) {
#pragma unroll
                for (int i = 0; i < 8; ++i) {
                    int f   = tid + 256 * i;
                    int row = f >> 5;
                    int c4  = f & 31;
                    *(float4*)&xs[row][c4 * 4] =
                        *(const float4*)(hbase + (size_t)row * (TT * HH) + kc * CK + c4 * 4);
                }
                __syncthreads();
                const float* xsrow = &xs[b][0];
                const float* wr = Whr + (size_t)j * HH + kc * CK;
                const float* wz = Whz + (size_t)j * HH + kc * CK;
                const float* wn = Whn + (size_t)j * HH + kc * CK;
#pragma unroll
                for (int k4 = 0; k4 < CK / 4; ++k4) {
                    float4 xv = *(const float4*)(xsrow + k4 * 4);
                    fma4(aR,  xv, *(const float4*)(wr + k4 * 4));
                    fma4(aZ,  xv, *(const float4*)(wz + k4 * 4));
                    fma4(aHN, xv, *(const float4*)(wn + k4 * 4));
                }
                __syncthreads();
            }
        }

        // epilogue (same order as r5 -> absmax unchanged)
        float rpre = (aR.x + aR.y + aR.z + aR.w) + xr + bir_j + bhr_j;
        float zpre = (aZ.x + aZ.y + aZ.z + aZ.w) + xz + biz_j + bhz_j;
        float hn   = (aHN.x + aHN.y + aHN.z + aHN.w) + bhn_j;
        float xn   = xn0 + bin_j;

        float r = 1.f / (1.f + __expf(-rpre));
        float z = 1.f / (1.f + __expf(-zpre));
        float n = tanhf(xn + r * hn);
        out[(size_t)b * (TT * HH) + (size_t)t * HH + j] = (1.f - z) * n + z * hprev;

        // ---- distributed-flag agent-scope barrier (no RMW, no hot line) ----
        __syncthreads();   // HIP barrier drains each wave's vmcnt first
        if (tid == 0) {
            __threadfence();                       // release: push writes to L3
            __hip_atomic_store(myflag, (unsigned)(t + 1),
                               __ATOMIC_RELAXED, __HIP_MEMORY_SCOPE_AGENT);
        }
        while (__hip_atomic_load(watch, __ATOMIC_RELAXED,
                                 __HIP_MEMORY_SCOPE_AGENT) < (unsigned)(t + 1))
            __builtin_amdgcn_s_sleep(2);
        if (tid == 0) __threadfence();             // acquire: inv stale lines
        __syncthreads();
    }
}

// ---------------------------------------------------------------------------
// Fallback A: r5's per-step h kernel (if coop launch is rejected).
// ---------------------------------------------------------------------------
__global__ __launch_bounds__(256) void gru_step_h(
    const float* __restrict__ Whr, const float* __restrict__ Whz,
    const float* __restrict__ Whn,
    const float* __restrict__ bir, const float* __restrict__ bhr,
    const float* __restrict__ biz, const float* __restrict__ bhz,
    const float* __restrict__ bin_, const float* __restrict__ bhn,
    const float* __restrict__ xpre,
    float* __restrict__ out, int t)
{
    __shared__ float xs[BB][PAD];
    const int tid = threadIdx.x;
    const int b   = tid & 63;
    const int jg  = tid >> 6;
    const int j   = __builtin_amdgcn_readfirstlane((int)blockIdx.x * JB + jg);

    const float bir_j = bir[j], bhr_j = bhr[j];
    const float biz_j = biz[j], bhz_j = bhz[j];
    const float bin_j = bin_[j], bhn_j = bhn[j];
    const float xr  = xpre[(((size_t)0 * TT + t) * HH + j) * BB + b];
    const float xz  = xpre[(((size_t)1 * TT + t) * HH + j) * BB + b];
    const float xn0 = xpre[(((size_t)2 * TT + t) * HH + j) * BB + b];
    float hprev = 0.f;
    if (t > 0)
        hprev = out[(size_t)b * (TT * HH) + (size_t)(t - 1) * HH + j];

    float4 aR  = {0.f, 0.f, 0.f, 0.f};
    float4 aZ  = {0.f, 0.f, 0.f, 0.f};
    float4 aHN = {0.f, 0.f, 0.f, 0.f};

    if (t > 0) {
        const float* hbase = out + (size_t)(t - 1) * HH;
        for (int kc = 0; kc < HH / CK; ++kc) {
#pragma unroll
            for (int i = 0; i < 8; ++i) {
                int f   = tid + 256 * i;
                int row = f >> 5;
                int c4  = f & 31;
                *(float4*)&xs[row][c4 * 4] =
                    *(const float4*)(hbase + (size_t)row * (TT * HH) + kc * CK + c4 * 4);
            }
            __syncthreads();
            const float* xsrow = &xs[b][0];
            const float* wr = Whr + (size_t)j * HH + kc * CK;
            const float* wz = Whz + (size_t)j * HH + kc * CK;
            const float* wn = Whn + (size_t)j * HH + kc * CK;
#pragma unroll
            for (int k4 = 0; k4 < CK / 4; ++k4) {
                float4 xv = *(const float4*)(xsrow + k4 * 4);
                fma4(aR,  xv, *(const float4*)(wr + k4 * 4));
                fma4(aZ,  xv, *(const float4*)(wz + k4 * 4));
                fma4(aHN, xv, *(const float4*)(wn + k4 * 4));
            }
            __syncthreads();
        }
    }

    float rpre = (aR.x + aR.y + aR.z + aR.w) + xr + bir_j + bhr_j;
    float zpre = (aZ.x + aZ.y + aZ.z + aZ.w) + xz + biz_j + bhz_j;
    float hn   = (aHN.x + aHN.y + aHN.z + aHN.w) + bhn_j;
    float xn   = xn0 + bin_j;

    float r = 1.f / (1.f + __expf(-rpre));
    float z = 1.f / (1.f + __expf(-zpre));
    float n = tanhf(xn + r * hn);

    out[(size_t)b * (TT * HH) + (size_t)t * HH + j] = (1.f - z) * n + z * hprev;
}

// ---------------------------------------------------------------------------
// Fallback B: r0 monolithic step (tiny ws).
// ---------------------------------------------------------------------------
__device__ __forceinline__ void accum_chunk(
    const float* __restrict__ xsrow,
    const float* __restrict__ wr, const float* __restrict__ wz,
    const float* __restrict__ wn,
    float4& aR, float4& aZ, float4& aN)
{
#pragma unroll
    for (int k4 = 0; k4 < CK / 4; ++k4) {
        float4 xv = *(const float4*)(xsrow + k4 * 4);
        fma4(aR, xv, *(const float4*)(wr + k4 * 4));
        fma4(aZ, xv, *(const float4*)(wz + k4 * 4));
        fma4(aN, xv, *(const float4*)(wn + k4 * 4));
    }
}

__global__ __launch_bounds__(256) void gru_step_full(
    const float* __restrict__ x,
    const float* __restrict__ Wir, const float* __restrict__ Whr,
    const float* __restrict__ Wiz, const float* __restrict__ Whz,
    const float* __restrict__ Win, const float* __restrict__ Whn,
    const float* __restrict__ bir, const float* __restrict__ bhr,
    const float* __restrict__ biz, const float* __restrict__ bhz,
    const float* __restrict__ bin_, const float* __restrict__ bhn,
    float* __restrict__ out, int t)
{
    __shared__ float xs[BB][PAD];
    const int tid = threadIdx.x;
    const int b   = tid & 63;
    const int jg  = tid >> 6;
    const int j   = __builtin_amdgcn_readfirstlane((int)blockIdx.x * JB + jg);

    float4 aR  = {0.f, 0.f, 0.f, 0.f};
    float4 aZ  = {0.f, 0.f, 0.f, 0.f};
    float4 aXN = {0.f, 0.f, 0.f, 0.f};
    float4 aHN = {0.f, 0.f, 0.f, 0.f};

    const float* xbase = x + (size_t)t * II;
    for (int kc = 0; kc < II / CK; ++kc) {
#pragma unroll
        for (int i = 0; i < 8; ++i) {
            int f   = tid + 256 * i;
            int row = f >> 5;
            int c4  = f & 31;
            *(float4*)&xs[row][c4 * 4] =
                *(const float4*)(xbase + (size_t)row * (TT * II) + kc * CK + c4 * 4);
        }
        __syncthreads();
        accum_chunk(&xs[b][0],
                    Wir + (size_t)j * II + kc * CK,
                    Wiz + (size_t)j * II + kc * CK,
                    Win + (size_t)j * II + kc * CK,
                    aR, aZ, aXN);
        __syncthreads();
    }

    if (t > 0) {
        const float* hbase = out + (size_t)(t - 1) * HH;
        for (int kc = 0; kc < HH / CK; ++kc) {
#pragma unroll
            for (int i = 0; i < 8; ++i) {
                int f   = tid + 256 * i;
                int row = f >> 5;
                int c4  = f & 31;
                *(float4*)&xs[row][c4 * 4] =
                    *(const float4*)(hbase + (size_t)row * (TT * HH) + kc * CK + c4 * 4);
            }
            __syncthreads();
            accum_chunk(&xs[b][0],
                        Whr + (size_t)j * HH + kc * CK,
                        Whz + (size_t)j * HH + kc * CK,
                        Whn + (size_t)j * HH + kc * CK,
                        aR, aZ, aHN);
            __syncthreads();
        }
    }

    float rpre = (aR.x + aR.y + aR.z + aR.w) + bir[j] + bhr[j];
    float zpre = (aZ.x + aZ.y + aZ.z + aZ.w) + biz[j] + bhz[j];
    float hn   = (aHN.x + aHN.y + aHN.z + aHN.w) + bhn[j];
    float xn   = (aXN.x + aXN.y + aXN.z + aXN.w) + bin_[j];

    float r = 1.f / (1.f + __expf(-rpre));
    float z = 1.f / (1.f + __expf(-zpre));
    float n = tanhf(xn + r * hn);

    float hprev = (t > 0) ? out[(size_t)b * (TT * HH) + (size_t)(t - 1) * HH + j] : 0.f;
    out[(size_t)b * (TT * HH) + (size_t)t * HH + j] = (1.f - z) * n + z * hprev;
}

extern "C" void kernel_launch(void* const* d_in, const int* in_sizes, int n_in,
                              void* d_out, int out_size, void* d_ws, size_t ws_size,
                              hipStream_t stream) {
    (void)in_sizes; (void)n_in; (void)out_size;

    const float* x    = (const float*)d_in[0];
    const float* Wir  = (const float*)d_in[1];
    const float* bir  = (const float*)d_in[2];
    const float* Whr  = (const float*)d_in[3];
    const float* bhr  = (const float*)d_in[4];
    const float* Wiz  = (const float*)d_in[5];
    const float* biz  = (const float*)d_in[6];
    const float* Whz  = (const float*)d_in[7];
    const float* bhz  = (const float*)d_in[8];
    const float* Win  = (const float*)d_in[9];
    const float* bin_ = (const float*)d_in[10];
    const float* Whn  = (const float*)d_in[11];
    const float* bhn  = (const float*)d_in[12];
    float* out = (float*)d_out;

    const size_t XPRE_BYTES = (size_t)3 * TT * HH * BB * sizeof(float);   // 402.65 MB
    const size_t FLAG_BYTES = (size_t)256 * FLAG_STRIDE * sizeof(unsigned); // 32 KB
    const size_t need = XPRE_BYTES + FLAG_BYTES;

    if (d_ws != nullptr && ws_size >= need) {
        float*    xpre  = (float*)d_ws;
        unsigned* flags = (unsigned*)((char*)d_ws + XPRE_BYTES);

        hipMemsetAsync(flags, 0, FLAG_BYTES, stream);
        xproj<<<dim3(TT * 64), dim3(256), 0, stream>>>(x, Wir, Wiz, Win, xpre);

        void* args[] = { (void*)&Whr, (void*)&Whz, (void*)&Whn,
                         (void*)&bir, (void*)&bhr, (void*)&biz, (void*)&bhz,
                         (void*)&bin_, (void*)&bhn, (void*)&xpre,
                         (void*)&out, (void*)&flags };
        hipError_t e = hipLaunchCooperativeKernel((const void*)gru_persist,
                                                  dim3(256), dim3(256),
                                                  args, 0, stream);
        if (e != hipSuccess) {
            for (int t = 0; t < TT; ++t) {
                gru_step_h<<<dim3(HH / JB), dim3(256), 0, stream>>>(
                    Whr, Whz, Whn, bir, bhr, biz, bhz, bin_, bhn, xpre, out, t);
            }
        }
    } else {
        for (int t = 0; t < TT; ++t) {
            gru_step_full<<<dim3(HH / JB), dim3(256), 0, stream>>>(
                x, Wir, Whr, Wiz, Whz, Win, Whn,
                bir, bhr, biz, bhz, bin_, bhn, out, t);
        }
    }
}

// Round 8
// 16499.345 us; speedup vs baseline: 2.3213x; 1.2685x over previous
//
#include <hip/hip_runtime.h>
#include <math.h>

// GRU layer: B=64, T=512, I=512, H=1024, fp32.
//
// Evidence ledger:
//  r1: cg::grid.sync persistent -> system-scope flush, 100us/step. Dead.
//  r5: 512 launches: ~20us fixed per-launch cost dominates. Dead end.
//  r6: persistent + single-counter atomic barrier: 65us/step (hot-line RMW).
//  r7: distributed flags: 36.7us/step; VALU-active ~5us -> ~30us/step left
//      = the __threadfence pair (buffer_wbl2 + buffer_inv L2 walks) and the
//      weight refetch they force.
//
// r8: fence-free data exchange via per-instruction coherence:
//   - h state in hpack[parity][b][k] (d_ws): written with sc0 sc1
//     through-stores (L3 coherence point), read with batched inline-asm
//     global_load_dwordx4 sc0 sc1 (bypass L2, 8 in flight, one waitcnt).
//   - s_waitcnt vmcnt(0) before the flag store replaces the release fence;
//     sc1 loads never allocate in L2 so no acquire fence is needed.
//   - weights + xpre keep normal cached loads -> L2-resident all 512 steps.
//   - barrier = r7's distributed monotonic flags (proven), minus fences.
//   - hprev comes free from the staged LDS tile (chunk kc == j>>7).
//   - accumulation order identical to r5/r7 -> absmax must stay 0.00390625.
// Fallbacks: coop-launch rejected -> r5 512-launch path; tiny ws -> r0.

#define BB 64
#define TT 512
#define II 512
#define HH 1024
#define JB 4
#define CK 128
#define PAD 132
#define XJ 16
#define FLAG_STRIDE 32   // uints; 128B between block flags

__device__ __forceinline__ void fma4(float4& a, const float4 xv, const float4 w) {
    a.x += xv.x * w.x;
    a.y += xv.y * w.y;
    a.z += xv.z * w.z;
    a.w += xv.w * w.w;
}

// 8 coherent (sc0 sc1: L2-bypass, L3 coherence point) 16B loads, one waitcnt.
// Addresses are a0 + i*8*HH floats (row stride 8 rows of hpack[b][k]).
__device__ __forceinline__ void stage8_sc1(float4 (&st)[8], const float* a0) {
    const float* a1 = a0 + (size_t)8 * HH;
    const float* a2 = a0 + (size_t)16 * HH;
    const float* a3 = a0 + (size_t)24 * HH;
    const float* a4 = a0 + (size_t)32 * HH;
    const float* a5 = a0 + (size_t)40 * HH;
    const float* a6 = a0 + (size_t)48 * HH;
    const float* a7 = a0 + (size_t)56 * HH;
    asm volatile(
        "global_load_dwordx4 %0, %8, off sc0 sc1\n\t"
        "global_load_dwordx4 %1, %9, off sc0 sc1\n\t"
        "global_load_dwordx4 %2, %10, off sc0 sc1\n\t"
        "global_load_dwordx4 %3, %11, off sc0 sc1\n\t"
        "global_load_dwordx4 %4, %12, off sc0 sc1\n\t"
        "global_load_dwordx4 %5, %13, off sc0 sc1\n\t"
        "global_load_dwordx4 %6, %14, off sc0 sc1\n\t"
        "global_load_dwordx4 %7, %15, off sc0 sc1\n\t"
        "s_waitcnt vmcnt(0)"
        : "=&v"(st[0]), "=&v"(st[1]), "=&v"(st[2]), "=&v"(st[3]),
          "=&v"(st[4]), "=&v"(st[5]), "=&v"(st[6]), "=&v"(st[7])
        : "v"(a0), "v"(a1), "v"(a2), "v"(a3),
          "v"(a4), "v"(a5), "v"(a6), "v"(a7)
        : "memory");
}

__device__ __forceinline__ void store_f32_sc1(float* p, float v) {
    asm volatile("global_store_dword %0, %1, off sc0 sc1"
                 :: "v"(p), "v"(v) : "memory");
}

// ---------------------------------------------------------------------------
// Phase 1: x-projections for all t (unchanged, proven).
// ---------------------------------------------------------------------------
__global__ __launch_bounds__(256) void xproj(
    const float* __restrict__ x,
    const float* __restrict__ Wir, const float* __restrict__ Wiz,
    const float* __restrict__ Win, float* __restrict__ xpre)
{
    __shared__ float xs[BB][PAD];
    const int tid  = threadIdx.x;
    const int b    = tid & 63;
    const int w    = tid >> 6;
    const int bid  = (int)blockIdx.x;
    const int t    = bid >> 6;
    const int jgrp = bid & 63;
    const int j0   = __builtin_amdgcn_readfirstlane(jgrp * XJ + w * 4);

    float4 acc[4][3];
#pragma unroll
    for (int jj = 0; jj < 4; ++jj)
#pragma unroll
        for (int g = 0; g < 3; ++g)
            acc[jj][g] = {0.f, 0.f, 0.f, 0.f};

    const float* xbase = x + (size_t)t * II;
    for (int kc = 0; kc < II / CK; ++kc) {
#pragma unroll
        for (int i = 0; i < 8; ++i) {
            int f   = tid + 256 * i;
            int row = f >> 5;
            int c4  = f & 31;
            *(float4*)&xs[row][c4 * 4] =
                *(const float4*)(xbase + (size_t)row * (TT * II) + kc * CK + c4 * 4);
        }
        __syncthreads();
        const float* xsrow = &xs[b][0];
#pragma unroll
        for (int k4 = 0; k4 < CK / 4; ++k4) {
            float4 xv = *(const float4*)(xsrow + k4 * 4);
#pragma unroll
            for (int jj = 0; jj < 4; ++jj) {
                const size_t wof = (size_t)(j0 + jj) * II + kc * CK + k4 * 4;
                fma4(acc[jj][0], xv, *(const float4*)(Wir + wof));
                fma4(acc[jj][1], xv, *(const float4*)(Wiz + wof));
                fma4(acc[jj][2], xv, *(const float4*)(Win + wof));
            }
        }
        __syncthreads();
    }

#pragma unroll
    for (int jj = 0; jj < 4; ++jj) {
        const int j = j0 + jj;
#pragma unroll
        for (int g = 0; g < 3; ++g) {
            float s = acc[jj][g].x + acc[jj][g].y + acc[jj][g].z + acc[jj][g].w;
            xpre[(((size_t)g * TT + t) * HH + j) * BB + b] = s;
        }
    }
}

// ---------------------------------------------------------------------------
// Phase 2: persistent recurrent kernel. Fence-free coherent h exchange.
// grid = 256 (1/CU, coop residency), 256 threads.
// ---------------------------------------------------------------------------
__global__ __launch_bounds__(256) void gru_persist(
    const float* __restrict__ Whr, const float* __restrict__ Whz,
    const float* __restrict__ Whn,
    const float* __restrict__ bir, const float* __restrict__ bhr,
    const float* __restrict__ biz, const float* __restrict__ bhz,
    const float* __restrict__ bin_, const float* __restrict__ bhn,
    const float* __restrict__ xpre,
    float* __restrict__ out, float* __restrict__ hpack,
    unsigned* __restrict__ flags)
{
    __shared__ float xs[BB][PAD];
    const int tid = threadIdx.x;
    const int b   = tid & 63;
    const int jg  = tid >> 6;
    const int bid = (int)blockIdx.x;
    const int j   = __builtin_amdgcn_readfirstlane(bid * JB + jg);

    const float bir_j = bir[j], bhr_j = bhr[j];
    const float biz_j = biz[j], bhz_j = bhz[j];
    const float bin_j = bin_[j], bhn_j = bhn[j];

    unsigned* myflag = flags + (size_t)bid * FLAG_STRIDE;
    unsigned* watch  = flags + (size_t)tid * FLAG_STRIDE;

    const size_t HB = (size_t)HH * BB;
    const int row0 = tid >> 5;         // 0..7
    const int c4   = tid & 31;
    const int kcj  = j >> 7;           // chunk holding k == j (wave-uniform)

    for (int t = 0; t < TT; ++t) {
        const float xr  = xpre[(((size_t)0 * TT + t) * HH + j) * BB + b];
        const float xz  = xpre[(((size_t)1 * TT + t) * HH + j) * BB + b];
        const float xn0 = xpre[(((size_t)2 * TT + t) * HH + j) * BB + b];

        float4 aR  = {0.f, 0.f, 0.f, 0.f};
        float4 aZ  = {0.f, 0.f, 0.f, 0.f};
        float4 aHN = {0.f, 0.f, 0.f, 0.f};
        float hprev = 0.f;

        if (t > 0) {
            const float* hp_prev = hpack + (size_t)((t + 1) & 1) * HB;  // (t-1)&1
#pragma unroll 1
            for (int kc = 0; kc < HH / CK; ++kc) {
                float4 st[8];
                stage8_sc1(st, hp_prev + (size_t)row0 * HH + kc * CK + c4 * 4);
#pragma unroll
                for (int i = 0; i < 8; ++i)
                    *(float4*)&xs[row0 + 8 * i][c4 * 4] = st[i];
                __syncthreads();
                if (kc == kcj) hprev = xs[b][j & 127];
                const float* xsrow = &xs[b][0];
                const float* wr = Whr + (size_t)j * HH + kc * CK;
                const float* wz = Whz + (size_t)j * HH + kc * CK;
                const float* wn = Whn + (size_t)j * HH + kc * CK;
#pragma unroll
                for (int k4 = 0; k4 < CK / 4; ++k4) {
                    float4 xv = *(const float4*)(xsrow + k4 * 4);
                    fma4(aR,  xv, *(const float4*)(wr + k4 * 4));
                    fma4(aZ,  xv, *(const float4*)(wz + k4 * 4));
                    fma4(aHN, xv, *(const float4*)(wn + k4 * 4));
                }
                __syncthreads();
            }
        }

        // epilogue (same order as r5/r7 -> absmax unchanged)
        float rpre = (aR.x + aR.y + aR.z + aR.w) + xr + bir_j + bhr_j;
        float zpre = (aZ.x + aZ.y + aZ.z + aZ.w) + xz + biz_j + bhz_j;
        float hn   = (aHN.x + aHN.y + aHN.z + aHN.w) + bhn_j;
        float xn   = xn0 + bin_j;

        float r = 1.f / (1.f + __expf(-rpre));
        float z = 1.f / (1.f + __expf(-zpre));
        float n = tanhf(xn + r * hn);
        float hnew = (1.f - z) * n + z * hprev;

        out[(size_t)b * (TT * HH) + (size_t)t * HH + j] = hnew;   // cached
        store_f32_sc1(hpack + (size_t)(t & 1) * HB + (size_t)b * HH + j, hnew);

        // ---- fence-free distributed-flag barrier ----
        asm volatile("s_waitcnt vmcnt(0)" ::: "memory");  // h at L3 before flag
        __syncthreads();
        if (tid == 0)
            __hip_atomic_store(myflag, (unsigned)(t + 1),
                               __ATOMIC_RELAXED, __HIP_MEMORY_SCOPE_AGENT);
        while (__hip_atomic_load(watch, __ATOMIC_RELAXED,
                                 __HIP_MEMORY_SCOPE_AGENT) < (unsigned)(t + 1))
            __builtin_amdgcn_s_sleep(2);
        __syncthreads();
    }
}

// ---------------------------------------------------------------------------
// Fallback A: r5's per-step h kernel (if coop launch is rejected).
// ---------------------------------------------------------------------------
__global__ __launch_bounds__(256) void gru_step_h(
    const float* __restrict__ Whr, const float* __restrict__ Whz,
    const float* __restrict__ Whn,
    const float* __restrict__ bir, const float* __restrict__ bhr,
    const float* __restrict__ biz, const float* __restrict__ bhz,
    const float* __restrict__ bin_, const float* __restrict__ bhn,
    const float* __restrict__ xpre,
    float* __restrict__ out, int t)
{
    __shared__ float xs[BB][PAD];
    const int tid = threadIdx.x;
    const int b   = tid & 63;
    const int jg  = tid >> 6;
    const int j   = __builtin_amdgcn_readfirstlane((int)blockIdx.x * JB + jg);

    const float bir_j = bir[j], bhr_j = bhr[j];
    const float biz_j = biz[j], bhz_j = bhz[j];
    const float bin_j = bin_[j], bhn_j = bhn[j];
    const float xr  = xpre[(((size_t)0 * TT + t) * HH + j) * BB + b];
    const float xz  = xpre[(((size_t)1 * TT + t) * HH + j) * BB + b];
    const float xn0 = xpre[(((size_t)2 * TT + t) * HH + j) * BB + b];
    float hprev = 0.f;
    if (t > 0)
        hprev = out[(size_t)b * (TT * HH) + (size_t)(t - 1) * HH + j];

    float4 aR  = {0.f, 0.f, 0.f, 0.f};
    float4 aZ  = {0.f, 0.f, 0.f, 0.f};
    float4 aHN = {0.f, 0.f, 0.f, 0.f};

    if (t > 0) {
        const float* hbase = out + (size_t)(t - 1) * HH;
        for (int kc = 0; kc < HH / CK; ++kc) {
#pragma unroll
            for (int i = 0; i < 8; ++i) {
                int f   = tid + 256 * i;
                int row = f >> 5;
                int cc  = f & 31;
                *(float4*)&xs[row][cc * 4] =
                    *(const float4*)(hbase + (size_t)row * (TT * HH) + kc * CK + cc * 4);
            }
            __syncthreads();
            const float* xsrow = &xs[b][0];
            const float* wr = Whr + (size_t)j * HH + kc * CK;
            const float* wz = Whz + (size_t)j * HH + kc * CK;
            const float* wn = Whn + (size_t)j * HH + kc * CK;
#pragma unroll
            for (int k4 = 0; k4 < CK / 4; ++k4) {
                float4 xv = *(const float4*)(xsrow + k4 * 4);
                fma4(aR,  xv, *(const float4*)(wr + k4 * 4));
                fma4(aZ,  xv, *(const float4*)(wz + k4 * 4));
                fma4(aHN, xv, *(const float4*)(wn + k4 * 4));
            }
            __syncthreads();
        }
    }

    float rpre = (aR.x + aR.y + aR.z + aR.w) + xr + bir_j + bhr_j;
    float zpre = (aZ.x + aZ.y + aZ.z + aZ.w) + xz + biz_j + bhz_j;
    float hn   = (aHN.x + aHN.y + aHN.z + aHN.w) + bhn_j;
    float xn   = xn0 + bin_j;

    float r = 1.f / (1.f + __expf(-rpre));
    float z = 1.f / (1.f + __expf(-zpre));
    float n = tanhf(xn + r * hn);

    out[(size_t)b * (TT * HH) + (size_t)t * HH + j] = (1.f - z) * n + z * hprev;
}

// ---------------------------------------------------------------------------
// Fallback B: r0 monolithic step (tiny ws).
// ---------------------------------------------------------------------------
__device__ __forceinline__ void accum_chunk(
    const float* __restrict__ xsrow,
    const float* __restrict__ wr, const float* __restrict__ wz,
    const float* __restrict__ wn,
    float4& aR, float4& aZ, float4& aN)
{
#pragma unroll
    for (int k4 = 0; k4 < CK / 4; ++k4) {
        float4 xv = *(const float4*)(xsrow + k4 * 4);
        fma4(aR, xv, *(const float4*)(wr + k4 * 4));
        fma4(aZ, xv, *(const float4*)(wz + k4 * 4));
        fma4(aN, xv, *(const float4*)(wn + k4 * 4));
    }
}

__global__ __launch_bounds__(256) void gru_step_full(
    const float* __restrict__ x,
    const float* __restrict__ Wir, const float* __restrict__ Whr,
    const float* __restrict__ Wiz, const float* __restrict__ Whz,
    const float* __restrict__ Win, const float* __restrict__ Whn,
    const float* __restrict__ bir, const float* __restrict__ bhr,
    const float* __restrict__ biz, const float* __restrict__ bhz,
    const float* __restrict__ bin_, const float* __restrict__ bhn,
    float* __restrict__ out, int t)
{
    __shared__ float xs[BB][PAD];
    const int tid = threadIdx.x;
    const int b   = tid & 63;
    const int jg  = tid >> 6;
    const int j   = __builtin_amdgcn_readfirstlane((int)blockIdx.x * JB + jg);

    float4 aR  = {0.f, 0.f, 0.f, 0.f};
    float4 aZ  = {0.f, 0.f, 0.f, 0.f};
    float4 aXN = {0.f, 0.f, 0.f, 0.f};
    float4 aHN = {0.f, 0.f, 0.f, 0.f};

    const float* xbase = x + (size_t)t * II;
    for (int kc = 0; kc < II / CK; ++kc) {
#pragma unroll
        for (int i = 0; i < 8; ++i) {
            int f   = tid + 256 * i;
            int row = f >> 5;
            int cc  = f & 31;
            *(float4*)&xs[row][cc * 4] =
                *(const float4*)(xbase + (size_t)row * (TT * II) + kc * CK + cc * 4);
        }
        __syncthreads();
        accum_chunk(&xs[b][0],
                    Wir + (size_t)j * II + kc * CK,
                    Wiz + (size_t)j * II + kc * CK,
                    Win + (size_t)j * II + kc * CK,
                    aR, aZ, aXN);
        __syncthreads();
    }

    if (t > 0) {
        const float* hbase = out + (size_t)(t - 1) * HH;
        for (int kc = 0; kc < HH / CK; ++kc) {
#pragma unroll
            for (int i = 0; i < 8; ++i) {
                int f   = tid + 256 * i;
                int row = f >> 5;
                int cc  = f & 31;
                *(float4*)&xs[row][cc * 4] =
                    *(const float4*)(hbase + (size_t)row * (TT * HH) + kc * CK + cc * 4);
            }
            __syncthreads();
            accum_chunk(&xs[b][0],
                        Whr + (size_t)j * HH + kc * CK,
                        Whz + (size_t)j * HH + kc * CK,
                        Whn + (size_t)j * HH + kc * CK,
                        aR, aZ, aHN);
            __syncthreads();
        }
    }

    float rpre = (aR.x + aR.y + aR.z + aR.w) + bir[j] + bhr[j];
    float zpre = (aZ.x + aZ.y + aZ.z + aZ.w) + biz[j] + bhz[j];
    float hn   = (aHN.x + aHN.y + aHN.z + aHN.w) + bhn[j];
    float xn   = (aXN.x + aXN.y + aXN.z + aXN.w) + bin_[j];

    float r = 1.f / (1.f + __expf(-rpre));
    float z = 1.f / (1.f + __expf(-zpre));
    float n = tanhf(xn + r * hn);

    float hprev = (t > 0) ? out[(size_t)b * (TT * HH) + (size_t)(t - 1) * HH + j] : 0.f;
    out[(size_t)b * (TT * HH) + (size_t)t * HH + j] = (1.f - z) * n + z * hprev;
}

extern "C" void kernel_launch(void* const* d_in, const int* in_sizes, int n_in,
                              void* d_out, int out_size, void* d_ws, size_t ws_size,
                              hipStream_t stream) {
    (void)in_sizes; (void)n_in; (void)out_size;

    const float* x    = (const float*)d_in[0];
    const float* Wir  = (const float*)d_in[1];
    const float* bir  = (const float*)d_in[2];
    const float* Whr  = (const float*)d_in[3];
    const float* bhr  = (const float*)d_in[4];
    const float* Wiz  = (const float*)d_in[5];
    const float* biz  = (const float*)d_in[6];
    const float* Whz  = (const float*)d_in[7];
    const float* bhz  = (const float*)d_in[8];
    const float* Win  = (const float*)d_in[9];
    const float* bin_ = (const float*)d_in[10];
    const float* Whn  = (const float*)d_in[11];
    const float* bhn  = (const float*)d_in[12];
    float* out = (float*)d_out;

    const size_t XPRE_BYTES  = (size_t)3 * TT * HH * BB * sizeof(float);    // 402.65 MB
    const size_t HPACK_BYTES = (size_t)2 * HH * BB * sizeof(float);         // 512 KB
    const size_t FLAG_BYTES  = (size_t)256 * FLAG_STRIDE * sizeof(unsigned); // 32 KB
    const size_t need = XPRE_BYTES + HPACK_BYTES + FLAG_BYTES;

    if (d_ws != nullptr && ws_size >= need) {
        float*    xpre  = (float*)d_ws;
        float*    hpack = (float*)((char*)d_ws + XPRE_BYTES);
        unsigned* flags = (unsigned*)((char*)d_ws + XPRE_BYTES + HPACK_BYTES);

        hipMemsetAsync(flags, 0, FLAG_BYTES, stream);
        xproj<<<dim3(TT * 64), dim3(256), 0, stream>>>(x, Wir, Wiz, Win, xpre);

        void* args[] = { (void*)&Whr, (void*)&Whz, (void*)&Whn,
                         (void*)&bir, (void*)&bhr, (void*)&biz, (void*)&bhz,
                         (void*)&bin_, (void*)&bhn, (void*)&xpre,
                         (void*)&out, (void*)&hpack, (void*)&flags };
        hipError_t e = hipLaunchCooperativeKernel((const void*)gru_persist,
                                                  dim3(256), dim3(256),
                                                  args, 0, stream);
        if (e != hipSuccess) {
            for (int t = 0; t < TT; ++t) {
                gru_step_h<<<dim3(HH / JB), dim3(256), 0, stream>>>(
                    Whr, Whz, Whn, bir, bhr, biz, bhz, bin_, bhn, xpre, out, t);
            }
        }
    } else {
        for (int t = 0; t < TT; ++t) {
            gru_step_full<<<dim3(HH / JB), dim3(256), 0, stream>>>(
                x, Wir, Whr, Wiz, Whz, Win, Whn,
                bir, bhr, biz, bhz, bin_, bhn, out, t);
        }
    }
}